// Round 1
// baseline (6630.275 us; speedup 1.0000x reference)
//
#include <hip/hip_runtime.h>

// ---------------- sizes / workspace layout (floats) ----------------
constexpr int BB   = 16;
constexpr int VS   = BB*3*32*32;     // 49152
constexpr int M1N  = BB*64*32*32;    // 1048576
constexpr int O1PN = BB*64*18*20;    // 368640 (padded 16x16 interior)
constexpr int M2N  = BB*128*16*16;   // 524288
constexpr int O2PN = BB*128*18*20;   // 737280
constexpr int M3N  = M2N;
constexpr int FBN  = BB*8192;        // 131072
constexpr int M4N  = BB*1024;
constexpr int M5N  = BB*1024;

constexpr int off_v   = 0;                 // x2 ping-pong
constexpr int off_s   = off_v   + 2*VS;
constexpr int off_m1  = off_s   + 2*VS;
constexpr int off_o1p = off_m1  + M1N;     // x2
constexpr int off_m2  = off_o1p + 2*O1PN;
constexpr int off_o2p = off_m2  + M2N;     // x2
constexpr int off_m3  = off_o2p + 2*O2PN;
constexpr int off_f   = off_m3  + M3N;     // x2
constexpr int off_m4  = off_f   + 2*FBN;
constexpr int off_o4  = off_m4  + M4N;     // x2
constexpr int off_m5  = off_o4  + 2*M4N;
constexpr int off_o5  = off_m5  + M5N;     // x2
constexpr int off_w1r = off_o5  + 2*M5N;   // zero-region ends here
constexpr int W1RN = 64*3*12;              // conv1: [co][ci][12]
constexpr int off_w2r = off_w1r + W1RN;
constexpr int W2RN = 8*64*256;             // conv2: [cog8][ci64][c16][16]
constexpr int off_w3r = off_w2r + W2RN;
constexpr int W3RN = 8*128*256;            // conv3: [cog8][ci128][c16][16]
constexpr int TOTF = off_w3r + W3RN;

__device__ __forceinline__ float4 ld4(const float* p){ return *reinterpret_cast<const float4*>(p); }
__device__ __forceinline__ float2 ld2(const float* p){ return *reinterpret_cast<const float2*>(p); }
__device__ __forceinline__ float spk(float m){ return m > 1.0f ? 1.0f : 0.0f; }

// async global->LDS, 16B per lane; LDS dest must be linear (base + lane*16)
__device__ __forceinline__ void gll16(const float* g, float* l) {
    __builtin_amdgcn_global_load_lds(
        (const __attribute__((address_space(1))) unsigned int*)g,
        (__attribute__((address_space(3))) unsigned int*)(unsigned int)(unsigned long long)l,
        16, 0, 0);
}

// ---------------- init: zero state, repack conv weights ----------------
__global__ __launch_bounds__(256) void init_k(const float* __restrict__ W1,
                                              const float* __restrict__ W2,
                                              const float* __restrict__ W3,
                                              float* __restrict__ ws,
                                              float* __restrict__ out) {
    int i0 = blockIdx.x*256 + threadIdx.x;
    int stride = gridDim.x*256;
    for (int p = i0; p < TOTF; p += stride) {
        float val = 0.0f;
        if (p >= off_w1r) {
            if (p < off_w2r) {               // conv1 [co][ci][12]
                int l = p - off_w1r, q = l/12, r = l%12;
                int dx = r & 3, dy = r >> 2;
                val = (dx < 3) ? W1[q*9 + dy*3 + dx] : 0.0f;
            } else if (p < off_w3r) {        // conv2 [cog][ci][c16][16]
                int l = p - off_w2r;
                int cog = l >> 14, rem = l & 16383;
                int ci = rem >> 8, rem2 = rem & 255, c16 = rem2 >> 4, r = rem2 & 15;
                int dy = r >> 2, dx = r & 3;
                int co = cog*16 + c16;
                val = (r < 12 && dx < 3) ? W2[(co*64 + ci)*9 + dy*3 + dx] : 0.0f;
            } else {                         // conv3 [cog][ci][c16][16]
                int l = p - off_w3r;
                int cog = l >> 15, rem = l & 32767;
                int ci = rem >> 8, rem2 = rem & 255, c16 = rem2 >> 4, r = rem2 & 15;
                int dy = r >> 2, dx = r & 3;
                int co = cog*16 + c16;
                val = (r < 12 && dx < 3) ? W3[(co*128 + ci)*9 + dy*3 + dx] : 0.0f;
            }
        }
        ws[p] = val;
    }
    if (i0 < 160) out[i0] = 0.0f;
}

// 3x3 FMA body for conv3: 2 co x (2y x 4x) outputs from rows UU/VV
#define C3_BODY(UU, VV, WQ)  do {                                              \
    float4 a0=ld4(WQ), a1=ld4((WQ)+4), a2=ld4((WQ)+8);                         \
    float4 b0=ld4((WQ)+16), b1=ld4((WQ)+20), b2=ld4((WQ)+24);                  \
    float wd[2][3][3] = {{{a0.x,a0.y,a0.z},{a1.x,a1.y,a1.z},{a2.x,a2.y,a2.z}}, \
                         {{b0.x,b0.y,b0.z},{b1.x,b1.y,b1.z},{b2.x,b2.y,b2.z}}};\
    float rv[4][6];                                                            \
    _Pragma("unroll") for (int r = 0; r < 4; ++r) {                            \
        rv[r][0]=UU[r].x; rv[r][1]=UU[r].y; rv[r][2]=UU[r].z;                  \
        rv[r][3]=UU[r].w; rv[r][4]=VV[r].x; rv[r][5]=VV[r].y; }                \
    _Pragma("unroll") for (int cc = 0; cc < 2; ++cc)                           \
      _Pragma("unroll") for (int iy = 0; iy < 2; ++iy)                         \
        _Pragma("unroll") for (int dy = 0; dy < 3; ++dy) {                     \
          int r = iy + dy;                                                     \
          _Pragma("unroll") for (int dx = 0; dx < 3; ++dx) {                   \
            float wvv = wd[cc][dy][dx];                                        \
            _Pragma("unroll") for (int p = 0; p < 4; ++p)                      \
              acc[cc][iy][p] += rv[r][p+dx]*wvv; } }                           \
} while(0)

#define C3_PF(UU, VV, PFCI) do { if ((PFCI) < 128) {                           \
    const float* rn = ip + (PFCI)*360;                                         \
    _Pragma("unroll") for (int r = 0; r < 4; ++r) {                            \
        UU[r]=ld4(rn+r*20); VV[r]=ld2(rn+r*20+4); } } } while(0)

// 3x3 FMA body for conv2: 2 co x (1y x 8x) outputs from rows RR/SS/TT
#define C2_BODY(RR, SS, TT, WQ) do {                                           \
    float4 a0=ld4(WQ), a1=ld4((WQ)+4), a2=ld4((WQ)+8);                         \
    float4 b0=ld4((WQ)+16), b1=ld4((WQ)+20), b2=ld4((WQ)+24);                  \
    float wd[2][3][3] = {{{a0.x,a0.y,a0.z},{a1.x,a1.y,a1.z},{a2.x,a2.y,a2.z}}, \
                         {{b0.x,b0.y,b0.z},{b1.x,b1.y,b1.z},{b2.x,b2.y,b2.z}}};\
    _Pragma("unroll") for (int dy = 0; dy < 3; ++dy) {                         \
        float rv[10] = {RR[dy].x,RR[dy].y,RR[dy].z,RR[dy].w,                   \
                        SS[dy].x,SS[dy].y,SS[dy].z,SS[dy].w,                   \
                        TT[dy].x,TT[dy].y};                                    \
        _Pragma("unroll") for (int cc = 0; cc < 2; ++cc)                       \
          _Pragma("unroll") for (int dx = 0; dx < 3; ++dx) {                   \
            float wvv = wd[cc][dy][dx];                                        \
            _Pragma("unroll") for (int p = 0; p < 8; ++p)                      \
              acc2[cc][p] += rv[p+dx]*wvv; } }                                 \
} while(0)

#define C2_PF(RR, SS, TT, PFCI) do { if ((PFCI) < 64) {                        \
    const float* rn = ip + (PFCI)*360;                                         \
    _Pragma("unroll") for (int dy = 0; dy < 3; ++dy) {                         \
        RR[dy]=ld4(rn+dy*20); SS[dy]=ld4(rn+dy*20+4); TT[dy]=ld2(rn+dy*20+8); } } } while(0)

// ---------------- one fused timestep ----------------
// bid map (longest blocks first): [0,128) conv3 | [128,256) conv2 | [256,384) fc1
//          [384,640) enc+conv1 | [640,896) fc2 | 896 fc3
__global__ __launch_bounds__(256) void step_k(const float* __restrict__ x,
                                              const float* __restrict__ L1,
                                              const float* __restrict__ L2,
                                              const float* __restrict__ L3,
                                              float* __restrict__ ws,
                                              float* __restrict__ out,
                                              int t) {
    const int rp = t & 1, wp = rp ^ 1;
    const int bid = blockIdx.x, tid = threadIdx.x;
    __shared__ __align__(16) float sh[8192];   // 32KB: conv dbuf 2x16KB | fc1 reduce 4x1056 | fc2 4608

    if (bid < 128) {
        // ---- conv3 (128->128) + LIF(m3) + pool: LDS-dbuf weights + 2-deep input prefetch ----
        int bb = bid, b = bb >> 3, cog = bb & 7;
        int cl = tid >> 5, rest = tid & 31, rpair = rest >> 2, cg = rest & 3;
        int y0 = rpair*2, x0 = cg*4;
        const float* ip = ws + off_o2p + rp*O2PN + b*128*360 + y0*20 + x0;
        const float* gw = ws + off_w3r + cog*32768;
        float acc[2][2][4] = {};
        float4 Au[4], Bu[4]; float2 Av[4], Bv[4];
        #pragma unroll
        for (int r = 0; r < 4; ++r) { Au[r] = ld4(ip + r*20);       Av[r] = ld2(ip + r*20 + 4); }
        #pragma unroll
        for (int r = 0; r < 4; ++r) { Bu[r] = ld4(ip + 360 + r*20); Bv[r] = ld2(ip + 360 + r*20 + 4); }
        #pragma unroll
        for (int q = 0; q < 4; ++q) gll16(gw + (q*256 + tid)*4, sh + (q*256 + tid)*4);
        for (int ch = 0; ch < 8; ++ch) {
            __syncthreads();                       // chunk ch landed; all waves done with other buf
            if (ch < 7) {                          // issue next chunk now, hidden under 16-ci compute
                const float* gs = gw + (ch + 1)*4096;
                float* ls = sh + ((ch + 1) & 1)*4096;
                #pragma unroll
                for (int q = 0; q < 4; ++q) gll16(gs + (q*256 + tid)*4, ls + (q*256 + tid)*4);
            }
            const float* wbase = sh + (ch & 1)*4096;
            #pragma unroll
            for (int cp = 0; cp < 8; ++cp) {
                const float* wq = wbase + cp*512 + cl*32;
                C3_BODY(Au, Av, wq);
                C3_PF(Au, Av, ch*16 + cp*2 + 2);
                C3_BODY(Bu, Bv, wq + 256);
                C3_PF(Bu, Bv, ch*16 + cp*2 + 3);
            }
        }
        #pragma unroll
        for (int cc = 0; cc < 2; ++cc) {
            int co = cog*16 + cl*2 + cc;
            float sp[2][4];
            #pragma unroll
            for (int iy = 0; iy < 2; ++iy)
                #pragma unroll
                for (int p = 0; p < 4; ++p) {
                    int gm = off_m3 + ((b*128 + co)*16 + y0 + iy)*16 + x0 + p;
                    float m = ws[gm], o = spk(m);
                    float mn = m + acc[cc][iy][p] - o;
                    ws[gm] = mn;
                    sp[iy][p] = spk(mn);
                }
            int fbase = off_f + wp*FBN + b*8192 + co*64 + (y0>>1)*8 + (x0>>1);
            ws[fbase+0] = (sp[0][0]+sp[0][1]+sp[1][0]+sp[1][1])*0.25f;
            ws[fbase+1] = (sp[0][2]+sp[0][3]+sp[1][2]+sp[1][3])*0.25f;
        }
    } else if (bid < 256) {
        // ---- conv2 (64->128) + LIF(m2): LDS-dbuf weights + 2-deep input prefetch ----
        int bb = bid - 128, b = bb >> 3, cog = bb & 7;
        int cl = tid >> 5, rest = tid & 31, y = rest >> 1, x0 = (rest & 1)*8;
        const float* ip = ws + off_o1p + rp*O1PN + b*64*360 + y*20 + x0;
        const float* gw = ws + off_w2r + cog*16384;
        float acc2[2][8] = {};
        float4 Ar[3], As[3], Br[3], Bs[3]; float2 At[3], Bt[3];
        #pragma unroll
        for (int dy = 0; dy < 3; ++dy) {
            Ar[dy] = ld4(ip + dy*20);       As[dy] = ld4(ip + dy*20 + 4);       At[dy] = ld2(ip + dy*20 + 8);
            Br[dy] = ld4(ip + 360 + dy*20); Bs[dy] = ld4(ip + 360 + dy*20 + 4); Bt[dy] = ld2(ip + 360 + dy*20 + 8);
        }
        #pragma unroll
        for (int q = 0; q < 4; ++q) gll16(gw + (q*256 + tid)*4, sh + (q*256 + tid)*4);
        for (int ch = 0; ch < 4; ++ch) {
            __syncthreads();
            if (ch < 3) {
                const float* gs = gw + (ch + 1)*4096;
                float* ls = sh + ((ch + 1) & 1)*4096;
                #pragma unroll
                for (int q = 0; q < 4; ++q) gll16(gs + (q*256 + tid)*4, ls + (q*256 + tid)*4);
            }
            const float* wbase = sh + (ch & 1)*4096;
            #pragma unroll
            for (int cp = 0; cp < 8; ++cp) {
                const float* wq = wbase + cp*512 + cl*32;
                C2_BODY(Ar, As, At, wq);
                C2_PF(Ar, As, At, ch*16 + cp*2 + 2);
                C2_BODY(Br, Bs, Bt, wq + 256);
                C2_PF(Br, Bs, Bt, ch*16 + cp*2 + 3);
            }
        }
        #pragma unroll
        for (int cc = 0; cc < 2; ++cc) {
            int co = cog*16 + cl*2 + cc;
            int mbase = off_m2 + ((b*128 + co)*16 + y)*16 + x0;
            int obase = off_o2p + wp*O2PN + ((b*128 + co)*18 + y + 1)*20 + x0 + 1;
            #pragma unroll
            for (int p = 0; p < 8; ++p) {
                float m = ws[mbase+p], o = spk(m);
                float mn = m + acc2[cc][p] - o;
                ws[mbase+p] = mn;
                ws[obase+p] = spk(mn);
            }
        }
    } else if (bid < 384) {
        // ---- fc1 8192->1024 + LIF(m4): barrier-free K-loop, acts from L2, 2-deep W prefetch ----
        int jb = bid - 256;
        int w = tid >> 6, l = tid & 63;
        const float* fp = ws + off_f + rp*FBN;
        const float* wb = L1 + (jb*8 + w*2)*8192;
        float acc[2][16] = {};
        float4 wA[2], wB[2];
        #pragma unroll
        for (int jj = 0; jj < 2; ++jj) {
            wA[jj] = ld4(wb + jj*8192 + l*4);
            wB[jj] = ld4(wb + jj*8192 + 256 + l*4);
        }
        for (int c = 0; c < 32; ++c) {
            const float* av = fp + c*256 + l*4;
            #pragma unroll
            for (int b = 0; b < 16; ++b) {
                float4 fv = ld4(av + b*8192);
                acc[0][b] += wA[0].x*fv.x + wA[0].y*fv.y + wA[0].z*fv.z + wA[0].w*fv.w;
                acc[1][b] += wA[1].x*fv.x + wA[1].y*fv.y + wA[1].z*fv.z + wA[1].w*fv.w;
            }
            wA[0] = wB[0]; wA[1] = wB[1];
            if (c < 30) {
                wB[0] = ld4(wb + (c+2)*256 + l*4);
                wB[1] = ld4(wb + 8192 + (c+2)*256 + l*4);
            }
        }
        // pair pre-reduce via shuffle, then stride-33 LDS reduce over 32 partials
        #pragma unroll
        for (int jj = 0; jj < 2; ++jj)
            #pragma unroll
            for (int b = 0; b < 16; ++b) acc[jj][b] += __shfl_xor(acc[jj][b], 1);
        float* rg = sh + w*1056;
        if ((l & 1) == 0) {
            #pragma unroll
            for (int jj = 0; jj < 2; ++jj)
                #pragma unroll
                for (int b = 0; b < 16; ++b) rg[(l>>1)*33 + jj*16 + b] = acc[jj][b];
        }
        __syncthreads();
        if (tid < 128) {
            int w2 = tid >> 5, r = tid & 31, jj = r >> 4, b = r & 15;
            const float* rg2 = sh + w2*1056;
            float sum = 0.0f;
            #pragma unroll
            for (int l2 = 0; l2 < 32; ++l2) sum += rg2[l2*33 + r];
            int j = jb*8 + w2*2 + jj;
            int gi = off_m4 + b*1024 + j;
            float m = ws[gi], o = spk(m);
            float mn = m + sum - o;
            ws[gi] = mn;
            ws[off_o4 + wp*M4N + b*1024 + j] = spk(mn);
        }
    } else if (bid < 640) {
        // ---- encoder (redundant) + conv1 + LIF(m1) + pooled next-spike ----
        int bb = bid - 384;
        int b = bb >> 4, tile = bb & 15;
        int ty = tile >> 2, tx = tile & 3;
        int y0 = ty*8, x0 = tx*8;
        const float* vin  = ws + off_v + rp*VS + b*3072;
        float*       vout = ws + off_v + wp*VS + b*3072;
        const float* sin_ = ws + off_s + rp*VS + b*3072;
        float*       sout = ws + off_s + wp*VS + b*3072;
        const float* xin  = x + b*3072;
        float* sl = sh; // [3][10][12]
        for (int idx = tid; idx < 300; idx += 256) {
            int ci = idx/100, r2 = idx%100, rr = r2/10, cc = r2%10;
            int yy = y0 - 1 + rr, xx = x0 - 1 + cc;
            float sv = 0.0f;
            if ((unsigned)yy < 32u && (unsigned)xx < 32u) {
                int g = ci*1024 + yy*32 + xx;
                float vn = vin[g] + xin[g] - sin_[g];
                sv = vn > 1.0f ? 1.0f : 0.0f;
                if (yy >= y0 && yy < y0+8 && xx >= x0 && xx < x0+8) { vout[g] = vn; sout[g] = sv; }
            }
            sl[(ci*10 + rr)*12 + cc] = sv;
        }
        __syncthreads();
        int tl = tid & 15, cog = tid >> 4;
        int py = (tl >> 2)*2, px = (tl & 3)*2;
        for (int cl = 0; cl < 4; ++cl) {
            int co = cog*4 + cl;
            const float* wtp = ws + off_w1r + co*36;
            float a00=0,a01=0,a10=0,a11=0;
            #pragma unroll
            for (int ci = 0; ci < 3; ++ci) {
                float4 w0 = ld4(wtp + ci*12), w1 = ld4(wtp + ci*12 + 4), w2 = ld4(wtp + ci*12 + 8);
                float wdl[3][3] = {{w0.x,w0.y,w0.z},{w1.x,w1.y,w1.z},{w2.x,w2.y,w2.z}};
                #pragma unroll
                for (int dy = 0; dy < 3; ++dy)
                    #pragma unroll
                    for (int dx = 0; dx < 3; ++dx) {
                        float wvv = wdl[dy][dx];
                        const float* rsl = sl + (ci*10 + py + dy)*12 + px + dx;
                        a00 += rsl[0]  * wvv; a01 += rsl[1]  * wvv;
                        a10 += rsl[12] * wvv; a11 += rsl[13] * wvv;
                    }
            }
            int gy = y0 + py, gx = x0 + px;
            float accs[2][2] = {{a00,a01},{a10,a11}};
            float pooled = 0.0f;
            #pragma unroll
            for (int iy = 0; iy < 2; ++iy)
                #pragma unroll
                for (int ix = 0; ix < 2; ++ix) {
                    int gm = off_m1 + ((b*64 + co)*32 + gy + iy)*32 + gx + ix;
                    float m = ws[gm], o = spk(m);
                    float mn = m + accs[iy][ix] - o;
                    ws[gm] = mn;
                    pooled += spk(mn);
                }
            ws[off_o1p + wp*O1PN + ((b*64 + co)*18 + (gy>>1) + 1)*20 + (gx>>1) + 1] = pooled*0.25f;
        }
    } else if (bid < 896) {
        // ---- fc2 1024->1024 + LIF(m5); 256 blocks x 4 cols, 64-lane K-split ----
        int jb = bid - 640;
        int jg = tid >> 6, l = tid & 63;
        int j  = jb*4 + jg;
        const float* op = ws + off_o4 + rp*M4N;
        const float* wr = L2 + j*1024;
        float acc[16] = {};
        float4 wv[4];
        #pragma unroll
        for (int u = 0; u < 4; ++u) wv[u] = ld4(wr + u*256 + l*4);
        #pragma unroll
        for (int u = 0; u < 4; ++u) {
            int k = u*256 + l*4;
            #pragma unroll
            for (int b = 0; b < 16; ++b) {
                float4 fv = ld4(op + b*1024 + k);
                acc[b] += wv[u].x*fv.x + wv[u].y*fv.y + wv[u].z*fv.z + wv[u].w*fv.w;
            }
        }
        int r = jg*64 + l;
        #pragma unroll
        for (int b = 0; b < 16; ++b) sh[r*17 + b] = acc[b];
        __syncthreads();
        {
            int p = tid >> 2, q = tid & 3;
            float s2 = 0.0f;
            int rb2 = (p >> 4)*64 + q*16, col = p & 15;
            #pragma unroll
            for (int t2 = 0; t2 < 16; ++t2) s2 += sh[(rb2 + t2)*17 + col];
            sh[4352 + tid] = s2;
        }
        __syncthreads();
        if (tid < 64) {
            float sum = sh[4352 + tid*4] + sh[4352 + tid*4 + 1]
                      + sh[4352 + tid*4 + 2] + sh[4352 + tid*4 + 3];
            int jg2 = tid >> 4, b = tid & 15;
            int jj = jb*4 + jg2;
            int gi = off_m5 + b*1024 + jj;
            float m = ws[gi], o = spk(m);
            float mn = m + sum - o;
            ws[gi] = mn;
            ws[off_o5 + wp*M5N + b*1024 + jj] = spk(mn);
        }
    } else {
        // ---- fc3 1024->10, accumulate output membrane ----
        if (tid < 160) {
            int b = tid/10, c = tid - b*10;
            const float* op = ws + off_o5 + rp*M5N + b*1024;
            const float* wr = L3 + c*1024;
            float sum = 0.0f;
            for (int k = 0; k < 1024; k += 4) {
                float4 a = ld4(op + k), wvv = ld4(wr + k);
                sum += a.x*wvv.x + a.y*wvv.y + a.z*wvv.z + a.w*wvv.w;
            }
            out[b*10 + c] += sum;
        }
    }
}

extern "C" void kernel_launch(void* const* d_in, const int* in_sizes, int n_in,
                              void* d_out, int out_size, void* d_ws, size_t ws_size,
                              hipStream_t stream) {
    const float* x  = (const float*)d_in[0];
    const float* W1 = (const float*)d_in[1];
    const float* W2 = (const float*)d_in[2];
    const float* W3 = (const float*)d_in[3];
    const float* L1 = (const float*)d_in[4];
    const float* L2 = (const float*)d_in[5];
    const float* L3 = (const float*)d_in[6];
    float* out = (float*)d_out;
    float* ws  = (float*)d_ws;

    init_k<<<1024, 256, 0, stream>>>(W1, W2, W3, ws, out);
    for (int t = 0; t < 20; ++t)
        step_k<<<897, 256, 0, stream>>>(x, L1, L2, L3, ws, out, t);
}

// Round 2
// 2231.571 us; speedup vs baseline: 2.9711x; 2.9711x over previous
//
#include <hip/hip_runtime.h>

// ---------------- sizes / workspace layout (floats) ----------------
constexpr int BB   = 16;
constexpr int VS   = BB*3*32*32;     // 49152
constexpr int M1N  = BB*64*32*32;    // 1048576
constexpr int O1PN = BB*64*18*20;    // 368640 (padded 16x16 interior)
constexpr int M2N  = BB*128*16*16;   // 524288
constexpr int O2PN = BB*128*18*20;   // 737280
constexpr int M3N  = M2N;
constexpr int FBN  = BB*8192;        // 131072
constexpr int M4N  = BB*1024;
constexpr int M5N  = BB*1024;

constexpr int off_v   = 0;                 // x2 ping-pong
constexpr int off_s   = off_v   + 2*VS;
constexpr int off_m1  = off_s   + 2*VS;
constexpr int off_o1p = off_m1  + M1N;     // x2
constexpr int off_m2  = off_o1p + 2*O1PN;
constexpr int off_o2p = off_m2  + M2N;     // x2
constexpr int off_m3  = off_o2p + 2*O2PN;
constexpr int off_f   = off_m3  + M3N;     // x2
constexpr int off_m4  = off_f   + 2*FBN;
constexpr int off_o4  = off_m4  + M4N;     // x2
constexpr int off_m5  = off_o4  + 2*M4N;
constexpr int off_o5  = off_m5  + M5N;     // x2
constexpr int off_w1r = off_o5  + 2*M5N;   // zero-region ends here
constexpr int W1RN = 64*3*12;              // conv1: [co][ci][12]
constexpr int off_w2r = off_w1r + W1RN;
constexpr int W2RN = 8*64*256;             // conv2: [cog8][ci64][c16][16]
constexpr int off_w3r = off_w2r + W2RN;
constexpr int W3RN = 8*128*256;            // conv3: [cog8][ci128][c16][16]
constexpr int TOTF = off_w3r + W3RN;

__device__ __forceinline__ float4 ld4(const float* p){ return *reinterpret_cast<const float4*>(p); }
__device__ __forceinline__ float2 ld2(const float* p){ return *reinterpret_cast<const float2*>(p); }
__device__ __forceinline__ float spk(float m){ return m > 1.0f ? 1.0f : 0.0f; }

// ---------------- init: zero state, repack conv weights ----------------
__global__ __launch_bounds__(256) void init_k(const float* __restrict__ W1,
                                              const float* __restrict__ W2,
                                              const float* __restrict__ W3,
                                              float* __restrict__ ws,
                                              float* __restrict__ out) {
    int i0 = blockIdx.x*256 + threadIdx.x;
    int stride = gridDim.x*256;
    for (int p = i0; p < TOTF; p += stride) {
        float val = 0.0f;
        if (p >= off_w1r) {
            if (p < off_w2r) {               // conv1 [co][ci][12]
                int l = p - off_w1r, q = l/12, r = l%12;
                int dx = r & 3, dy = r >> 2;
                val = (dx < 3) ? W1[q*9 + dy*3 + dx] : 0.0f;
            } else if (p < off_w3r) {        // conv2 [cog][ci][c16][16]
                int l = p - off_w2r;
                int cog = l >> 14, rem = l & 16383;
                int ci = rem >> 8, rem2 = rem & 255, c16 = rem2 >> 4, r = rem2 & 15;
                int dy = r >> 2, dx = r & 3;
                int co = cog*16 + c16;
                val = (r < 12 && dx < 3) ? W2[(co*64 + ci)*9 + dy*3 + dx] : 0.0f;
            } else {                         // conv3 [cog][ci][c16][16]
                int l = p - off_w3r;
                int cog = l >> 15, rem = l & 32767;
                int ci = rem >> 8, rem2 = rem & 255, c16 = rem2 >> 4, r = rem2 & 15;
                int dy = r >> 2, dx = r & 3;
                int co = cog*16 + c16;
                val = (r < 12 && dx < 3) ? W3[(co*128 + ci)*9 + dy*3 + dx] : 0.0f;
            }
        }
        ws[p] = val;
    }
    if (i0 < 160) out[i0] = 0.0f;
}

// ---------------- one fused timestep ----------------
// bid map (longest blocks first):
//   [0,256)     conv3 split: (b, cog, half) -> 8 co each, no LDS, no barriers
//   [256,512)   conv2 split: (b, cog, half) -> 8 co each, no LDS, no barriers
//   [512,640)   fc1 (barrier-free K-loop)
//   [640,896)   enc + conv1
//   [896,1152)  fc2
//   1152        fc3
__global__ __launch_bounds__(256) void step_k(const float* __restrict__ x,
                                              const float* __restrict__ L1,
                                              const float* __restrict__ L2,
                                              const float* __restrict__ L3,
                                              float* __restrict__ ws,
                                              float* __restrict__ out,
                                              int t) {
    const int rp = t & 1, wp = rp ^ 1;
    const int bid = blockIdx.x, tid = threadIdx.x;
    __shared__ __align__(16) float sh[4608];   // 18KB: fc1 reduce 4x1056 | fc2 4608 | enc 360

    if (bid < 256) {
        // ---- conv3 (128->128) + LIF(m3) + pool: 256 blocks x 8 co, weights direct from L2 ----
        int b = bid >> 4, sub = bid & 15, cog = sub >> 1, h = sub & 1;
        int cl = tid >> 5, rest = tid & 31, rpair = rest >> 2, cg = rest & 3;
        int y0 = rpair*2, x0 = cg*4;
        int co = cog*16 + h*8 + cl;
        const float* ip  = ws + off_o2p + rp*O2PN + b*128*360 + y0*20 + x0;
        const float* wpt = ws + off_w3r + cog*32768 + (h*8 + cl)*16;   // + ci*256 per ci
        float acc[2][4] = {};
        float4 nu[4]; float2 nv[4];
        float4 nw0, nw1, nw2;
        #pragma unroll
        for (int r = 0; r < 4; ++r) { nu[r] = ld4(ip + r*20); nv[r] = ld2(ip + r*20 + 4); }
        nw0 = ld4(wpt); nw1 = ld4(wpt + 4); nw2 = ld4(wpt + 8);
        for (int ci = 0; ci < 128; ++ci) {
            float4 cu[4]; float2 cv[4];
            float4 w0 = nw0, w1 = nw1, w2 = nw2;
            #pragma unroll
            for (int r = 0; r < 4; ++r) { cu[r] = nu[r]; cv[r] = nv[r]; }
            if (ci < 127) {
                const float* rn = ip + (ci + 1)*360;
                #pragma unroll
                for (int r = 0; r < 4; ++r) { nu[r] = ld4(rn + r*20); nv[r] = ld2(rn + r*20 + 4); }
                const float* wn = wpt + (ci + 1)*256;
                nw0 = ld4(wn); nw1 = ld4(wn + 4); nw2 = ld4(wn + 8);
            }
            float wd[3][3] = {{w0.x,w0.y,w0.z},{w1.x,w1.y,w1.z},{w2.x,w2.y,w2.z}};
            float rv[4][6];
            #pragma unroll
            for (int r = 0; r < 4; ++r) {
                rv[r][0]=cu[r].x; rv[r][1]=cu[r].y; rv[r][2]=cu[r].z;
                rv[r][3]=cu[r].w; rv[r][4]=cv[r].x; rv[r][5]=cv[r].y;
            }
            #pragma unroll
            for (int iy = 0; iy < 2; ++iy)
                #pragma unroll
                for (int dy = 0; dy < 3; ++dy) {
                    int r = iy + dy;
                    #pragma unroll
                    for (int dx = 0; dx < 3; ++dx) {
                        float wvv = wd[dy][dx];
                        #pragma unroll
                        for (int p = 0; p < 4; ++p) acc[iy][p] += rv[r][p+dx]*wvv;
                    }
                }
        }
        float sp[2][4];
        #pragma unroll
        for (int iy = 0; iy < 2; ++iy)
            #pragma unroll
            for (int p = 0; p < 4; ++p) {
                int gm = off_m3 + ((b*128 + co)*16 + y0 + iy)*16 + x0 + p;
                float m = ws[gm], o = spk(m);
                float mn = m + acc[iy][p] - o;
                ws[gm] = mn;
                sp[iy][p] = spk(mn);
            }
        int fbase = off_f + wp*FBN + b*8192 + co*64 + (y0>>1)*8 + (x0>>1);
        ws[fbase+0] = (sp[0][0]+sp[0][1]+sp[1][0]+sp[1][1])*0.25f;
        ws[fbase+1] = (sp[0][2]+sp[0][3]+sp[1][2]+sp[1][3])*0.25f;
    } else if (bid < 512) {
        // ---- conv2 (64->128) + LIF(m2): 256 blocks x 8 co, weights direct from L2 ----
        int bb = bid - 256, b = bb >> 4, sub = bb & 15, cog = sub >> 1, h = sub & 1;
        int cl = tid >> 5, rest = tid & 31, y = rest >> 1, x0 = (rest & 1)*8;
        int co = cog*16 + h*8 + cl;
        const float* ip  = ws + off_o1p + rp*O1PN + b*64*360 + y*20 + x0;
        const float* wpt = ws + off_w2r + cog*16384 + (h*8 + cl)*16;
        float acc2[8] = {};
        float4 nr[3], ns[3]; float2 nt2[3];
        float4 nw0, nw1, nw2;
        #pragma unroll
        for (int dy = 0; dy < 3; ++dy) {
            nr[dy] = ld4(ip + dy*20); ns[dy] = ld4(ip + dy*20 + 4); nt2[dy] = ld2(ip + dy*20 + 8);
        }
        nw0 = ld4(wpt); nw1 = ld4(wpt + 4); nw2 = ld4(wpt + 8);
        for (int ci = 0; ci < 64; ++ci) {
            float4 cr[3], cs[3]; float2 ct[3];
            float4 w0 = nw0, w1 = nw1, w2 = nw2;
            #pragma unroll
            for (int dy = 0; dy < 3; ++dy) { cr[dy] = nr[dy]; cs[dy] = ns[dy]; ct[dy] = nt2[dy]; }
            if (ci < 63) {
                const float* rn = ip + (ci + 1)*360;
                #pragma unroll
                for (int dy = 0; dy < 3; ++dy) {
                    nr[dy] = ld4(rn + dy*20); ns[dy] = ld4(rn + dy*20 + 4); nt2[dy] = ld2(rn + dy*20 + 8);
                }
                const float* wn = wpt + (ci + 1)*256;
                nw0 = ld4(wn); nw1 = ld4(wn + 4); nw2 = ld4(wn + 8);
            }
            float wd[3][3] = {{w0.x,w0.y,w0.z},{w1.x,w1.y,w1.z},{w2.x,w2.y,w2.z}};
            #pragma unroll
            for (int dy = 0; dy < 3; ++dy) {
                float rv[10] = {cr[dy].x,cr[dy].y,cr[dy].z,cr[dy].w,
                                cs[dy].x,cs[dy].y,cs[dy].z,cs[dy].w,
                                ct[dy].x,ct[dy].y};
                #pragma unroll
                for (int dx = 0; dx < 3; ++dx) {
                    float wvv = wd[dy][dx];
                    #pragma unroll
                    for (int p = 0; p < 8; ++p) acc2[p] += rv[p+dx]*wvv;
                }
            }
        }
        int mbase = off_m2 + ((b*128 + co)*16 + y)*16 + x0;
        int obase = off_o2p + wp*O2PN + ((b*128 + co)*18 + y + 1)*20 + x0 + 1;
        #pragma unroll
        for (int p = 0; p < 8; ++p) {
            float m = ws[mbase+p], o = spk(m);
            float mn = m + acc2[p] - o;
            ws[mbase+p] = mn;
            ws[obase+p] = spk(mn);
        }
    } else if (bid < 640) {
        // ---- fc1 8192->1024 + LIF(m4): barrier-free K-loop, acts from L2, 2-deep W prefetch ----
        int jb = bid - 512;
        int w = tid >> 6, l = tid & 63;
        const float* fp = ws + off_f + rp*FBN;
        const float* wb = L1 + (jb*8 + w*2)*8192;
        float acc[2][16] = {};
        float4 wA[2], wB[2];
        #pragma unroll
        for (int jj = 0; jj < 2; ++jj) {
            wA[jj] = ld4(wb + jj*8192 + l*4);
            wB[jj] = ld4(wb + jj*8192 + 256 + l*4);
        }
        for (int c = 0; c < 32; ++c) {
            const float* av = fp + c*256 + l*4;
            #pragma unroll
            for (int b = 0; b < 16; ++b) {
                float4 fv = ld4(av + b*8192);
                acc[0][b] += wA[0].x*fv.x + wA[0].y*fv.y + wA[0].z*fv.z + wA[0].w*fv.w;
                acc[1][b] += wA[1].x*fv.x + wA[1].y*fv.y + wA[1].z*fv.z + wA[1].w*fv.w;
            }
            wA[0] = wB[0]; wA[1] = wB[1];
            if (c < 30) {
                wB[0] = ld4(wb + (c+2)*256 + l*4);
                wB[1] = ld4(wb + 8192 + (c+2)*256 + l*4);
            }
        }
        // pair pre-reduce via shuffle, then stride-33 LDS reduce over 32 partials
        #pragma unroll
        for (int jj = 0; jj < 2; ++jj)
            #pragma unroll
            for (int b = 0; b < 16; ++b) acc[jj][b] += __shfl_xor(acc[jj][b], 1);
        float* rg = sh + w*1056;
        if ((l & 1) == 0) {
            #pragma unroll
            for (int jj = 0; jj < 2; ++jj)
                #pragma unroll
                for (int b = 0; b < 16; ++b) rg[(l>>1)*33 + jj*16 + b] = acc[jj][b];
        }
        __syncthreads();
        if (tid < 128) {
            int w2 = tid >> 5, r = tid & 31, jj = r >> 4, b = r & 15;
            const float* rg2 = sh + w2*1056;
            float sum = 0.0f;
            #pragma unroll
            for (int l2 = 0; l2 < 32; ++l2) sum += rg2[l2*33 + r];
            int j = jb*8 + w2*2 + jj;
            int gi = off_m4 + b*1024 + j;
            float m = ws[gi], o = spk(m);
            float mn = m + sum - o;
            ws[gi] = mn;
            ws[off_o4 + wp*M4N + b*1024 + j] = spk(mn);
        }
    } else if (bid < 896) {
        // ---- encoder (redundant) + conv1 + LIF(m1) + pooled next-spike ----
        int bb = bid - 640;
        int b = bb >> 4, tile = bb & 15;
        int ty = tile >> 2, tx = tile & 3;
        int y0 = ty*8, x0 = tx*8;
        const float* vin  = ws + off_v + rp*VS + b*3072;
        float*       vout = ws + off_v + wp*VS + b*3072;
        const float* sin_ = ws + off_s + rp*VS + b*3072;
        float*       sout = ws + off_s + wp*VS + b*3072;
        const float* xin  = x + b*3072;
        float* sl = sh; // [3][10][12]
        for (int idx = tid; idx < 300; idx += 256) {
            int ci = idx/100, r2 = idx%100, rr = r2/10, cc = r2%10;
            int yy = y0 - 1 + rr, xx = x0 - 1 + cc;
            float sv = 0.0f;
            if ((unsigned)yy < 32u && (unsigned)xx < 32u) {
                int g = ci*1024 + yy*32 + xx;
                float vn = vin[g] + xin[g] - sin_[g];
                sv = vn > 1.0f ? 1.0f : 0.0f;
                if (yy >= y0 && yy < y0+8 && xx >= x0 && xx < x0+8) { vout[g] = vn; sout[g] = sv; }
            }
            sl[(ci*10 + rr)*12 + cc] = sv;
        }
        __syncthreads();
        int tl = tid & 15, cog = tid >> 4;
        int py = (tl >> 2)*2, px = (tl & 3)*2;
        for (int cl = 0; cl < 4; ++cl) {
            int co = cog*4 + cl;
            const float* wtp = ws + off_w1r + co*36;
            float a00=0,a01=0,a10=0,a11=0;
            #pragma unroll
            for (int ci = 0; ci < 3; ++ci) {
                float4 w0 = ld4(wtp + ci*12), w1 = ld4(wtp + ci*12 + 4), w2 = ld4(wtp + ci*12 + 8);
                float wdl[3][3] = {{w0.x,w0.y,w0.z},{w1.x,w1.y,w1.z},{w2.x,w2.y,w2.z}};
                #pragma unroll
                for (int dy = 0; dy < 3; ++dy)
                    #pragma unroll
                    for (int dx = 0; dx < 3; ++dx) {
                        float wvv = wdl[dy][dx];
                        const float* rsl = sl + (ci*10 + py + dy)*12 + px + dx;
                        a00 += rsl[0]  * wvv; a01 += rsl[1]  * wvv;
                        a10 += rsl[12] * wvv; a11 += rsl[13] * wvv;
                    }
            }
            int gy = y0 + py, gx = x0 + px;
            float accs[2][2] = {{a00,a01},{a10,a11}};
            float pooled = 0.0f;
            #pragma unroll
            for (int iy = 0; iy < 2; ++iy)
                #pragma unroll
                for (int ix = 0; ix < 2; ++ix) {
                    int gm = off_m1 + ((b*64 + co)*32 + gy + iy)*32 + gx + ix;
                    float m = ws[gm], o = spk(m);
                    float mn = m + accs[iy][ix] - o;
                    ws[gm] = mn;
                    pooled += spk(mn);
                }
            ws[off_o1p + wp*O1PN + ((b*64 + co)*18 + (gy>>1) + 1)*20 + (gx>>1) + 1] = pooled*0.25f;
        }
    } else if (bid < 1152) {
        // ---- fc2 1024->1024 + LIF(m5); 256 blocks x 4 cols, 64-lane K-split ----
        int jb = bid - 896;
        int jg = tid >> 6, l = tid & 63;
        int j  = jb*4 + jg;
        const float* op = ws + off_o4 + rp*M4N;
        const float* wr = L2 + j*1024;
        float acc[16] = {};
        float4 wv[4];
        #pragma unroll
        for (int u = 0; u < 4; ++u) wv[u] = ld4(wr + u*256 + l*4);
        #pragma unroll
        for (int u = 0; u < 4; ++u) {
            int k = u*256 + l*4;
            #pragma unroll
            for (int b = 0; b < 16; ++b) {
                float4 fv = ld4(op + b*1024 + k);
                acc[b] += wv[u].x*fv.x + wv[u].y*fv.y + wv[u].z*fv.z + wv[u].w*fv.w;
            }
        }
        int r = jg*64 + l;
        #pragma unroll
        for (int b = 0; b < 16; ++b) sh[r*17 + b] = acc[b];
        __syncthreads();
        {
            int p = tid >> 2, q = tid & 3;
            float s2 = 0.0f;
            int rb2 = (p >> 4)*64 + q*16, col = p & 15;
            #pragma unroll
            for (int t2 = 0; t2 < 16; ++t2) s2 += sh[(rb2 + t2)*17 + col];
            sh[4352 + tid] = s2;
        }
        __syncthreads();
        if (tid < 64) {
            float sum = sh[4352 + tid*4] + sh[4352 + tid*4 + 1]
                      + sh[4352 + tid*4 + 2] + sh[4352 + tid*4 + 3];
            int jg2 = tid >> 4, b = tid & 15;
            int jj = jb*4 + jg2;
            int gi = off_m5 + b*1024 + jj;
            float m = ws[gi], o = spk(m);
            float mn = m + sum - o;
            ws[gi] = mn;
            ws[off_o5 + wp*M5N + b*1024 + jj] = spk(mn);
        }
    } else {
        // ---- fc3 1024->10, accumulate output membrane ----
        if (tid < 160) {
            int b = tid/10, c = tid - b*10;
            const float* op = ws + off_o5 + rp*M5N + b*1024;
            const float* wr = L3 + c*1024;
            float sum = 0.0f;
            for (int k = 0; k < 1024; k += 4) {
                float4 a = ld4(op + k), wvv = ld4(wr + k);
                sum += a.x*wvv.x + a.y*wvv.y + a.z*wvv.z + a.w*wvv.w;
            }
            out[b*10 + c] += sum;
        }
    }
}

extern "C" void kernel_launch(void* const* d_in, const int* in_sizes, int n_in,
                              void* d_out, int out_size, void* d_ws, size_t ws_size,
                              hipStream_t stream) {
    const float* x  = (const float*)d_in[0];
    const float* W1 = (const float*)d_in[1];
    const float* W2 = (const float*)d_in[2];
    const float* W3 = (const float*)d_in[3];
    const float* L1 = (const float*)d_in[4];
    const float* L2 = (const float*)d_in[5];
    const float* L3 = (const float*)d_in[6];
    float* out = (float*)d_out;
    float* ws  = (float*)d_ws;

    init_k<<<1024, 256, 0, stream>>>(W1, W2, W3, ws, out);
    for (int t = 0; t < 20; ++t)
        step_k<<<1153, 256, 0, stream>>>(x, L1, L2, L3, ws, out, t);
}

// Round 3
// 2159.016 us; speedup vs baseline: 3.0710x; 1.0336x over previous
//
#include <hip/hip_runtime.h>

// ---------------- sizes / workspace layout (floats) ----------------
constexpr int BB   = 16;
constexpr int VS   = BB*3*32*32;     // 49152
constexpr int M1N  = BB*64*32*32;    // 1048576
constexpr int O1PN = BB*64*18*20;    // 368640 (padded 16x16 interior)
constexpr int M2N  = BB*128*16*16;   // 524288
constexpr int O2PN = BB*128*18*20;   // 737280
constexpr int M3N  = M2N;
constexpr int FBN  = BB*8192;        // 131072
constexpr int M4N  = BB*1024;
constexpr int M5N  = BB*1024;

constexpr int off_v   = 0;                 // x2 ping-pong
constexpr int off_s   = off_v   + 2*VS;
constexpr int off_m1  = off_s   + 2*VS;
constexpr int off_o1p = off_m1  + M1N;     // x2
constexpr int off_m2  = off_o1p + 2*O1PN;
constexpr int off_o2p = off_m2  + M2N;     // x2
constexpr int off_m3  = off_o2p + 2*O2PN;
constexpr int off_f   = off_m3  + M3N;     // x2
constexpr int off_m4  = off_f   + 2*FBN;
constexpr int off_o4  = off_m4  + M4N;     // x2
constexpr int off_m5  = off_o4  + 2*M4N;
constexpr int off_o5  = off_m5  + M5N;     // x2
constexpr int off_w1r = off_o5  + 2*M5N;   // zero-region ends here
constexpr int W1RN = 64*3*12;              // conv1: [co][ci][12]
constexpr int off_w2r = off_w1r + W1RN;
constexpr int W2RN = 8*64*256;             // conv2: [cog8][ci64][c16][16]
constexpr int off_w3r = off_w2r + W2RN;
constexpr int W3RN = 8*128*256;            // conv3: [cog8][ci128][c16][16]
constexpr int TOTF = off_w3r + W3RN;

__device__ __forceinline__ float4 ld4(const float* p){ return *reinterpret_cast<const float4*>(p); }
__device__ __forceinline__ float2 ld2(const float* p){ return *reinterpret_cast<const float2*>(p); }
__device__ __forceinline__ float spk(float m){ return m > 1.0f ? 1.0f : 0.0f; }

// ---------------- init: zero state, repack conv weights ----------------
__global__ __launch_bounds__(256) void init_k(const float* __restrict__ W1,
                                              const float* __restrict__ W2,
                                              const float* __restrict__ W3,
                                              float* __restrict__ ws,
                                              float* __restrict__ out) {
    int i0 = blockIdx.x*256 + threadIdx.x;
    int stride = gridDim.x*256;
    for (int p = i0; p < TOTF; p += stride) {
        float val = 0.0f;
        if (p >= off_w1r) {
            if (p < off_w2r) {               // conv1 [co][ci][12]
                int l = p - off_w1r, q = l/12, r = l%12;
                int dx = r & 3, dy = r >> 2;
                val = (dx < 3) ? W1[q*9 + dy*3 + dx] : 0.0f;
            } else if (p < off_w3r) {        // conv2 [cog][ci][c16][16]
                int l = p - off_w2r;
                int cog = l >> 14, rem = l & 16383;
                int ci = rem >> 8, rem2 = rem & 255, c16 = rem2 >> 4, r = rem2 & 15;
                int dy = r >> 2, dx = r & 3;
                int co = cog*16 + c16;
                val = (r < 12 && dx < 3) ? W2[(co*64 + ci)*9 + dy*3 + dx] : 0.0f;
            } else {                         // conv3 [cog][ci][c16][16]
                int l = p - off_w3r;
                int cog = l >> 15, rem = l & 32767;
                int ci = rem >> 8, rem2 = rem & 255, c16 = rem2 >> 4, r = rem2 & 15;
                int dy = r >> 2, dx = r & 3;
                int co = cog*16 + c16;
                val = (r < 12 && dx < 3) ? W3[(co*128 + ci)*9 + dy*3 + dx] : 0.0f;
            }
        }
        ws[p] = val;
    }
    if (i0 < 160) out[i0] = 0.0f;
}

// load 3 padded input rows (6 floats each) into register set SET (u=float4, v=float2)
#define CV_LOAD(SETu, SETv, PTR) do {                                          \
    SETu[0]=ld4(PTR);      SETv[0]=ld2((PTR)+4);                               \
    SETu[1]=ld4((PTR)+20); SETv[1]=ld2((PTR)+24);                              \
    SETu[2]=ld4((PTR)+40); SETv[2]=ld2((PTR)+44); } while(0)

// one ci step: prefetch ci+1 into NXT, load weights for 2 co, FMA from CUR
#define CV_STEP(CURu, CURv, NXTu, NXTv, CI, NCI) do {                          \
    if ((CI) + 1 < (NCI)) {                                                    \
        const float* rn_ = ip + ((CI) + 1)*360;                                \
        CV_LOAD(NXTu, NXTv, rn_);                                              \
    }                                                                          \
    const float* wq_ = wpt + (CI)*256;                                         \
    float4 wa0=ld4(wq_),    wa1=ld4(wq_+4),  wa2=ld4(wq_+8);                   \
    float4 wb0=ld4(wq_+16), wb1=ld4(wq_+20), wb2=ld4(wq_+24);                  \
    float rv[3][6];                                                            \
    _Pragma("unroll") for (int r_ = 0; r_ < 3; ++r_) {                         \
        rv[r_][0]=CURu[r_].x; rv[r_][1]=CURu[r_].y; rv[r_][2]=CURu[r_].z;      \
        rv[r_][3]=CURu[r_].w; rv[r_][4]=CURv[r_].x; rv[r_][5]=CURv[r_].y; }    \
    float wda[3][3] = {{wa0.x,wa0.y,wa0.z},{wa1.x,wa1.y,wa1.z},{wa2.x,wa2.y,wa2.z}}; \
    float wdb[3][3] = {{wb0.x,wb0.y,wb0.z},{wb1.x,wb1.y,wb1.z},{wb2.x,wb2.y,wb2.z}}; \
    _Pragma("unroll") for (int dy_ = 0; dy_ < 3; ++dy_)                        \
        _Pragma("unroll") for (int dx_ = 0; dx_ < 3; ++dx_) {                  \
            float wva = wda[dy_][dx_], wvb = wdb[dy_][dx_];                    \
            _Pragma("unroll") for (int p_ = 0; p_ < 4; ++p_) {                 \
                acc[0][p_] += rv[dy_][p_+dx_]*wva;                             \
                acc[1][p_] += rv[dy_][p_+dx_]*wvb; } }                         \
} while(0)

// ---------------- one fused timestep ----------------
// bid map (longest blocks first):
//   [0,256)     conv3 y-split: (b, cog, yh) 16 co x 8 rows, no LDS/barriers
//   [256,512)   conv2 y-split: (b, cog, yh) 16 co x 8 rows, no LDS/barriers
//   [512,640)   fc1 (barrier-free K-loop)
//   [640,896)   enc + conv1
//   [896,1152)  fc2
//   1152        fc3
__global__ __launch_bounds__(256) void step_k(const float* __restrict__ x,
                                              const float* __restrict__ L1,
                                              const float* __restrict__ L2,
                                              const float* __restrict__ L3,
                                              float* __restrict__ ws,
                                              float* __restrict__ out,
                                              int t) {
    const int rp = t & 1, wp = rp ^ 1;
    const int bid = blockIdx.x, tid = threadIdx.x;
    __shared__ __align__(16) float sh[4608];   // 18KB: fc1 reduce 4x1056 | fc2 4608 | enc 360

    if (bid < 256) {
        // ---- conv3 (128->128) + LIF(m3) + pool; 2co x 1y x 4x per lane ----
        int b = bid >> 4, sub = bid & 15, cog = sub >> 1, yh = sub & 1;
        int cl = tid >> 5, rest = tid & 31, yl = rest >> 2, cg = rest & 3;
        int y = yh*8 + yl, x0 = cg*4;
        int co = cog*16 + cl*2;
        const float* ip  = ws + off_o2p + rp*O2PN + b*128*360 + y*20 + x0;
        const float* wpt = ws + off_w3r + cog*32768 + cl*32;
        float acc[2][4] = {};
        float4 Au[3], Bu[3]; float2 Av[3], Bv[3];
        CV_LOAD(Au, Av, ip);
        for (int ci = 0; ci < 128; ci += 2) {
            CV_STEP(Au, Av, Bu, Bv, ci,     128);
            CV_STEP(Bu, Bv, Au, Av, ci + 1, 128);
        }
        #pragma unroll
        for (int cc = 0; cc < 2; ++cc) {
            float sp[4];
            #pragma unroll
            for (int p = 0; p < 4; ++p) {
                int gm = off_m3 + ((b*128 + co + cc)*16 + y)*16 + x0 + p;
                float m = ws[gm], o = spk(m);
                float mn = m + acc[cc][p] - o;
                ws[gm] = mn;
                sp[p] = spk(mn);
            }
            float pl = sp[0] + sp[1], ph = sp[2] + sp[3];
            float ql = __shfl_xor(pl, 4), qh = __shfl_xor(ph, 4);
            if ((yl & 1) == 0) {
                int fbase = off_f + wp*FBN + b*8192 + (co + cc)*64 + (y>>1)*8 + (x0>>1);
                ws[fbase+0] = (pl + ql)*0.25f;
                ws[fbase+1] = (ph + qh)*0.25f;
            }
        }
    } else if (bid < 512) {
        // ---- conv2 (64->128) + LIF(m2); 2co x 1y x 4x per lane ----
        int bb = bid - 256, b = bb >> 4, sub = bb & 15, cog = sub >> 1, yh = sub & 1;
        int cl = tid >> 5, rest = tid & 31, yl = rest >> 2, cg = rest & 3;
        int y = yh*8 + yl, x0 = cg*4;
        int co = cog*16 + cl*2;
        const float* ip  = ws + off_o1p + rp*O1PN + b*64*360 + y*20 + x0;
        const float* wpt = ws + off_w2r + cog*16384 + cl*32;
        float acc[2][4] = {};
        float4 Au[3], Bu[3]; float2 Av[3], Bv[3];
        CV_LOAD(Au, Av, ip);
        for (int ci = 0; ci < 64; ci += 2) {
            CV_STEP(Au, Av, Bu, Bv, ci,     64);
            CV_STEP(Bu, Bv, Au, Av, ci + 1, 64);
        }
        #pragma unroll
        for (int cc = 0; cc < 2; ++cc) {
            int mbase = off_m2 + ((b*128 + co + cc)*16 + y)*16 + x0;
            int obase = off_o2p + wp*O2PN + ((b*128 + co + cc)*18 + y + 1)*20 + x0 + 1;
            #pragma unroll
            for (int p = 0; p < 4; ++p) {
                float m = ws[mbase+p], o = spk(m);
                float mn = m + acc[cc][p] - o;
                ws[mbase+p] = mn;
                ws[obase+p] = spk(mn);
            }
        }
    } else if (bid < 640) {
        // ---- fc1 8192->1024 + LIF(m4): barrier-free K-loop, acts from L2, 2-deep W prefetch ----
        int jb = bid - 512;
        int w = tid >> 6, l = tid & 63;
        const float* fp = ws + off_f + rp*FBN;
        const float* wb = L1 + (jb*8 + w*2)*8192;
        float acc[2][16] = {};
        float4 wA[2], wB[2];
        #pragma unroll
        for (int jj = 0; jj < 2; ++jj) {
            wA[jj] = ld4(wb + jj*8192 + l*4);
            wB[jj] = ld4(wb + jj*8192 + 256 + l*4);
        }
        for (int c = 0; c < 32; ++c) {
            const float* av = fp + c*256 + l*4;
            #pragma unroll
            for (int b = 0; b < 16; ++b) {
                float4 fv = ld4(av + b*8192);
                acc[0][b] += wA[0].x*fv.x + wA[0].y*fv.y + wA[0].z*fv.z + wA[0].w*fv.w;
                acc[1][b] += wA[1].x*fv.x + wA[1].y*fv.y + wA[1].z*fv.z + wA[1].w*fv.w;
            }
            wA[0] = wB[0]; wA[1] = wB[1];
            if (c < 30) {
                wB[0] = ld4(wb + (c+2)*256 + l*4);
                wB[1] = ld4(wb + 8192 + (c+2)*256 + l*4);
            }
        }
        // pair pre-reduce via shuffle, then stride-33 LDS reduce over 32 partials
        #pragma unroll
        for (int jj = 0; jj < 2; ++jj)
            #pragma unroll
            for (int b = 0; b < 16; ++b) acc[jj][b] += __shfl_xor(acc[jj][b], 1);
        float* rg = sh + w*1056;
        if ((l & 1) == 0) {
            #pragma unroll
            for (int jj = 0; jj < 2; ++jj)
                #pragma unroll
                for (int b = 0; b < 16; ++b) rg[(l>>1)*33 + jj*16 + b] = acc[jj][b];
        }
        __syncthreads();
        if (tid < 128) {
            int w2 = tid >> 5, r = tid & 31, jj = r >> 4, b = r & 15;
            const float* rg2 = sh + w2*1056;
            float sum = 0.0f;
            #pragma unroll
            for (int l2 = 0; l2 < 32; ++l2) sum += rg2[l2*33 + r];
            int j = jb*8 + w2*2 + jj;
            int gi = off_m4 + b*1024 + j;
            float m = ws[gi], o = spk(m);
            float mn = m + sum - o;
            ws[gi] = mn;
            ws[off_o4 + wp*M4N + b*1024 + j] = spk(mn);
        }
    } else if (bid < 896) {
        // ---- encoder (redundant) + conv1 + LIF(m1) + pooled next-spike ----
        int bb = bid - 640;
        int b = bb >> 4, tile = bb & 15;
        int ty = tile >> 2, tx = tile & 3;
        int y0 = ty*8, x0 = tx*8;
        const float* vin  = ws + off_v + rp*VS + b*3072;
        float*       vout = ws + off_v + wp*VS + b*3072;
        const float* sin_ = ws + off_s + rp*VS + b*3072;
        float*       sout = ws + off_s + wp*VS + b*3072;
        const float* xin  = x + b*3072;
        float* sl = sh; // [3][10][12]
        for (int idx = tid; idx < 300; idx += 256) {
            int ci = idx/100, r2 = idx%100, rr = r2/10, cc = r2%10;
            int yy = y0 - 1 + rr, xx = x0 - 1 + cc;
            float sv = 0.0f;
            if ((unsigned)yy < 32u && (unsigned)xx < 32u) {
                int g = ci*1024 + yy*32 + xx;
                float vn = vin[g] + xin[g] - sin_[g];
                sv = vn > 1.0f ? 1.0f : 0.0f;
                if (yy >= y0 && yy < y0+8 && xx >= x0 && xx < x0+8) { vout[g] = vn; sout[g] = sv; }
            }
            sl[(ci*10 + rr)*12 + cc] = sv;
        }
        __syncthreads();
        int tl = tid & 15, cog = tid >> 4;
        int py = (tl >> 2)*2, px = (tl & 3)*2;
        for (int cl = 0; cl < 4; ++cl) {
            int co = cog*4 + cl;
            const float* wtp = ws + off_w1r + co*36;
            float a00=0,a01=0,a10=0,a11=0;
            #pragma unroll
            for (int ci = 0; ci < 3; ++ci) {
                float4 w0 = ld4(wtp + ci*12), w1 = ld4(wtp + ci*12 + 4), w2 = ld4(wtp + ci*12 + 8);
                float wdl[3][3] = {{w0.x,w0.y,w0.z},{w1.x,w1.y,w1.z},{w2.x,w2.y,w2.z}};
                #pragma unroll
                for (int dy = 0; dy < 3; ++dy)
                    #pragma unroll
                    for (int dx = 0; dx < 3; ++dx) {
                        float wvv = wdl[dy][dx];
                        const float* rsl = sl + (ci*10 + py + dy)*12 + px + dx;
                        a00 += rsl[0]  * wvv; a01 += rsl[1]  * wvv;
                        a10 += rsl[12] * wvv; a11 += rsl[13] * wvv;
                    }
            }
            int gy = y0 + py, gx = x0 + px;
            float accs[2][2] = {{a00,a01},{a10,a11}};
            float pooled = 0.0f;
            #pragma unroll
            for (int iy = 0; iy < 2; ++iy)
                #pragma unroll
                for (int ix = 0; ix < 2; ++ix) {
                    int gm = off_m1 + ((b*64 + co)*32 + gy + iy)*32 + gx + ix;
                    float m = ws[gm], o = spk(m);
                    float mn = m + accs[iy][ix] - o;
                    ws[gm] = mn;
                    pooled += spk(mn);
                }
            ws[off_o1p + wp*O1PN + ((b*64 + co)*18 + (gy>>1) + 1)*20 + (gx>>1) + 1] = pooled*0.25f;
        }
    } else if (bid < 1152) {
        // ---- fc2 1024->1024 + LIF(m5); 256 blocks x 4 cols, 64-lane K-split ----
        int jb = bid - 896;
        int jg = tid >> 6, l = tid & 63;
        int j  = jb*4 + jg;
        const float* op = ws + off_o4 + rp*M4N;
        const float* wr = L2 + j*1024;
        float acc[16] = {};
        float4 wv[4];
        #pragma unroll
        for (int u = 0; u < 4; ++u) wv[u] = ld4(wr + u*256 + l*4);
        #pragma unroll
        for (int u = 0; u < 4; ++u) {
            int k = u*256 + l*4;
            #pragma unroll
            for (int b = 0; b < 16; ++b) {
                float4 fv = ld4(op + b*1024 + k);
                acc[b] += wv[u].x*fv.x + wv[u].y*fv.y + wv[u].z*fv.z + wv[u].w*fv.w;
            }
        }
        int r = jg*64 + l;
        #pragma unroll
        for (int b = 0; b < 16; ++b) sh[r*17 + b] = acc[b];
        __syncthreads();
        {
            int p = tid >> 2, q = tid & 3;
            float s2 = 0.0f;
            int rb2 = (p >> 4)*64 + q*16, col = p & 15;
            #pragma unroll
            for (int t2 = 0; t2 < 16; ++t2) s2 += sh[(rb2 + t2)*17 + col];
            sh[4352 + tid] = s2;
        }
        __syncthreads();
        if (tid < 64) {
            float sum = sh[4352 + tid*4] + sh[4352 + tid*4 + 1]
                      + sh[4352 + tid*4 + 2] + sh[4352 + tid*4 + 3];
            int jg2 = tid >> 4, b = tid & 15;
            int jj = jb*4 + jg2;
            int gi = off_m5 + b*1024 + jj;
            float m = ws[gi], o = spk(m);
            float mn = m + sum - o;
            ws[gi] = mn;
            ws[off_o5 + wp*M5N + b*1024 + jj] = spk(mn);
        }
    } else {
        // ---- fc3 1024->10, accumulate output membrane ----
        if (tid < 160) {
            int b = tid/10, c = tid - b*10;
            const float* op = ws + off_o5 + rp*M5N + b*1024;
            const float* wr = L3 + c*1024;
            float sum = 0.0f;
            for (int k = 0; k < 1024; k += 4) {
                float4 a = ld4(op + k), wvv = ld4(wr + k);
                sum += a.x*wvv.x + a.y*wvv.y + a.z*wvv.z + a.w*wvv.w;
            }
            out[b*10 + c] += sum;
        }
    }
}

extern "C" void kernel_launch(void* const* d_in, const int* in_sizes, int n_in,
                              void* d_out, int out_size, void* d_ws, size_t ws_size,
                              hipStream_t stream) {
    const float* x  = (const float*)d_in[0];
    const float* W1 = (const float*)d_in[1];
    const float* W2 = (const float*)d_in[2];
    const float* W3 = (const float*)d_in[3];
    const float* L1 = (const float*)d_in[4];
    const float* L2 = (const float*)d_in[5];
    const float* L3 = (const float*)d_in[6];
    float* out = (float*)d_out;
    float* ws  = (float*)d_ws;

    init_k<<<1024, 256, 0, stream>>>(W1, W2, W3, ws, out);
    for (int t = 0; t < 20; ++t)
        step_k<<<1153, 256, 0, stream>>>(x, L1, L2, L3, ws, out, t);
}

// Round 4
// 1824.777 us; speedup vs baseline: 3.6335x; 1.1832x over previous
//
#include <hip/hip_runtime.h>

// ---------------- sizes / workspace layout (floats) ----------------
constexpr int BB   = 16;
constexpr int VS   = BB*3*32*32;     // 49152
constexpr int M1N  = BB*64*32*32;    // 1048576
constexpr int O1PN = BB*64*18*20;    // 368640 (padded 16x16 interior)
constexpr int M2N  = BB*128*16*16;   // 524288
constexpr int O2PN = BB*128*18*20;   // 737280
constexpr int M3N  = M2N;
constexpr int FBN  = BB*8192;        // 131072
constexpr int M4N  = BB*1024;
constexpr int M5N  = BB*1024;

constexpr int off_v   = 0;                 // x2 ping-pong
constexpr int off_s   = off_v   + 2*VS;
constexpr int off_m1  = off_s   + 2*VS;
constexpr int off_o1p = off_m1  + M1N;     // x2
constexpr int off_m2  = off_o1p + 2*O1PN;
constexpr int off_o2p = off_m2  + M2N;     // x2
constexpr int off_m3  = off_o2p + 2*O2PN;
constexpr int off_f   = off_m3  + M3N;     // x2
constexpr int off_m4  = off_f   + 2*FBN;
constexpr int off_o4  = off_m4  + M4N;     // x2
constexpr int off_m5  = off_o4  + 2*M4N;
constexpr int off_o5  = off_m5  + M5N;     // x2
constexpr int off_w1r = off_o5  + 2*M5N;   // zero-region ends here
constexpr int W1RN = 64*3*12;              // conv1: [co][ci][12]
// conv2/conv3: compact co-pair records [cog8][pair8][ci][20]
//   record: co_even w0..8 | co_odd w0..8 | 2 pad
constexpr int off_w2r = off_w1r + W1RN;
constexpr int W2RN = 8*8*64*20;            // 81920
constexpr int off_w3r = off_w2r + W2RN;
constexpr int W3RN = 8*8*128*20;           // 163840
constexpr int TOTF = off_w3r + W3RN;

__device__ __forceinline__ float4 ld4(const float* p){ return *reinterpret_cast<const float4*>(p); }
__device__ __forceinline__ float2 ld2(const float* p){ return *reinterpret_cast<const float2*>(p); }
__device__ __forceinline__ float spk(float m){ return m > 1.0f ? 1.0f : 0.0f; }

// ---------------- init: zero state, repack conv weights ----------------
__global__ __launch_bounds__(256) void init_k(const float* __restrict__ W1,
                                              const float* __restrict__ W2,
                                              const float* __restrict__ W3,
                                              float* __restrict__ ws,
                                              float* __restrict__ out) {
    int i0 = blockIdx.x*256 + threadIdx.x;
    int stride = gridDim.x*256;
    for (int p = i0; p < TOTF; p += stride) {
        float val = 0.0f;
        if (p >= off_w1r) {
            if (p < off_w2r) {               // conv1 [co][ci][12]
                int l = p - off_w1r, q = l/12, r = l%12;
                int dx = r & 3, dy = r >> 2;
                val = (dx < 3) ? W1[q*9 + dy*3 + dx] : 0.0f;
            } else if (p < off_w3r) {        // conv2 pair records
                int l = p - off_w2r;
                int cog = l / 10240, rem = l % 10240;
                int pr = rem / 1280, rem2 = rem % 1280;
                int ci = rem2 / 20, k = rem2 % 20;
                if (k < 18) {
                    int co = cog*16 + pr*2 + (k >= 9 ? 1 : 0);
                    int kk = k >= 9 ? k - 9 : k;
                    val = W2[(co*64 + ci)*9 + kk];
                }
            } else {                         // conv3 pair records
                int l = p - off_w3r;
                int cog = l / 20480, rem = l % 20480;
                int pr = rem / 2560, rem2 = rem % 2560;
                int ci = rem2 / 20, k = rem2 % 20;
                if (k < 18) {
                    int co = cog*16 + pr*2 + (k >= 9 ? 1 : 0);
                    int kk = k >= 9 ? k - 9 : k;
                    val = W3[(co*128 + ci)*9 + kk];
                }
            }
        }
        ws[p] = val;
    }
    if (i0 < 160) out[i0] = 0.0f;
}

// ---- conv macros: 4 input rows (6 wide), 2 co, 2y x 4x outputs, A/B pipelined ----
#define CV4_LOAD(Iu, Iv, PTR) do {                                             \
    _Pragma("unroll") for (int r_ = 0; r_ < 4; ++r_) {                         \
        Iu[r_] = ld4((PTR) + r_*20); Iv[r_] = ld2((PTR) + r_*20 + 4); } } while(0)

#define CVW_LOAD(W, WQ) do {                                                   \
    _Pragma("unroll") for (int q_ = 0; q_ < 5; ++q_) W[q_] = ld4((WQ) + q_*4); } while(0)

#define CV4_FMA(Iu, Iv, W) do {                                                \
    float rv[4][6];                                                            \
    _Pragma("unroll") for (int r_ = 0; r_ < 4; ++r_) {                         \
        rv[r_][0]=Iu[r_].x; rv[r_][1]=Iu[r_].y; rv[r_][2]=Iu[r_].z;            \
        rv[r_][3]=Iu[r_].w; rv[r_][4]=Iv[r_].x; rv[r_][5]=Iv[r_].y; }          \
    float wd[2][9] = {{W[0].x,W[0].y,W[0].z,W[0].w,W[1].x,W[1].y,W[1].z,W[1].w,W[2].x}, \
                      {W[2].y,W[2].z,W[2].w,W[3].x,W[3].y,W[3].z,W[3].w,W[4].x,W[4].y}}; \
    _Pragma("unroll") for (int cc_ = 0; cc_ < 2; ++cc_)                        \
      _Pragma("unroll") for (int iy_ = 0; iy_ < 2; ++iy_)                      \
        _Pragma("unroll") for (int dy_ = 0; dy_ < 3; ++dy_)                    \
          _Pragma("unroll") for (int dx_ = 0; dx_ < 3; ++dx_) {                \
            float wv_ = wd[cc_][dy_*3+dx_];                                    \
            _Pragma("unroll") for (int p_ = 0; p_ < 4; ++p_)                   \
              acc[cc_][iy_][p_] += rv[iy_+dy_][p_+dx_]*wv_; } } while(0)

// ---------------- one fused timestep ----------------
// bid map (longest blocks first): [0,128) conv3 | [128,256) conv2 | [256,384) fc1
//          [384,640) enc+conv1 | [640,896) fc2 | 896 fc3
__global__ __launch_bounds__(256) void step_k(const float* __restrict__ x,
                                              const float* __restrict__ L1,
                                              const float* __restrict__ L2,
                                              const float* __restrict__ L3,
                                              float* __restrict__ ws,
                                              float* __restrict__ out,
                                              int t) {
    const int rp = t & 1, wp = rp ^ 1;
    const int bid = blockIdx.x, tid = threadIdx.x;
    __shared__ __align__(16) float sh[4608];   // 18KB: fc1 reduce 4x1056 | fc2 4608 | enc 360

    if (bid < 128) {
        // ---- conv3 (128->128) + LIF(m3) + pool; 2co x 2y x 4x per lane, no LDS/barriers ----
        int b = bid >> 3, cog = bid & 7;
        int cl = tid >> 5, rest = tid & 31, rpair = rest >> 2, cg = rest & 3;
        int y0 = rpair*2, x0 = cg*4;
        int co = cog*16 + cl*2;
        const float* ip  = ws + off_o2p + rp*O2PN + b*128*360 + y0*20 + x0;
        const float* wpt = ws + off_w3r + (cog*8 + cl)*128*20;
        float acc[2][2][4] = {};
        float4 IAu[4], IBu[4]; float2 IAv[4], IBv[4];
        float4 WA[5], WB[5];
        CV4_LOAD(IAu, IAv, ip);
        CVW_LOAD(WA, wpt);
        CV4_LOAD(IBu, IBv, ip + 360);
        CVW_LOAD(WB, wpt + 20);
        #pragma unroll 1
        for (int ci = 0; ci < 128; ci += 2) {
            CV4_FMA(IAu, IAv, WA);
            if (ci + 2 < 128) {
                CV4_LOAD(IAu, IAv, ip + (ci + 2)*360);
                CVW_LOAD(WA, wpt + (ci + 2)*20);
            }
            CV4_FMA(IBu, IBv, WB);
            if (ci + 3 < 128) {
                CV4_LOAD(IBu, IBv, ip + (ci + 3)*360);
                CVW_LOAD(WB, wpt + (ci + 3)*20);
            }
        }
        #pragma unroll
        for (int cc = 0; cc < 2; ++cc) {
            float sp[2][4];
            #pragma unroll
            for (int iy = 0; iy < 2; ++iy)
                #pragma unroll
                for (int p = 0; p < 4; ++p) {
                    int gm = off_m3 + ((b*128 + co + cc)*16 + y0 + iy)*16 + x0 + p;
                    float m = ws[gm], o = spk(m);
                    float mn = m + acc[cc][iy][p] - o;
                    ws[gm] = mn;
                    sp[iy][p] = spk(mn);
                }
            int fbase = off_f + wp*FBN + b*8192 + (co + cc)*64 + (y0>>1)*8 + (x0>>1);
            ws[fbase+0] = (sp[0][0]+sp[0][1]+sp[1][0]+sp[1][1])*0.25f;
            ws[fbase+1] = (sp[0][2]+sp[0][3]+sp[1][2]+sp[1][3])*0.25f;
        }
    } else if (bid < 256) {
        // ---- conv2 (64->128) + LIF(m2); 2co x 2y x 4x per lane, no LDS/barriers ----
        int bb = bid - 128, b = bb >> 3, cog = bb & 7;
        int cl = tid >> 5, rest = tid & 31, rpair = rest >> 2, cg = rest & 3;
        int y0 = rpair*2, x0 = cg*4;
        int co = cog*16 + cl*2;
        const float* ip  = ws + off_o1p + rp*O1PN + b*64*360 + y0*20 + x0;
        const float* wpt = ws + off_w2r + (cog*8 + cl)*64*20;
        float acc[2][2][4] = {};
        float4 IAu[4], IBu[4]; float2 IAv[4], IBv[4];
        float4 WA[5], WB[5];
        CV4_LOAD(IAu, IAv, ip);
        CVW_LOAD(WA, wpt);
        CV4_LOAD(IBu, IBv, ip + 360);
        CVW_LOAD(WB, wpt + 20);
        #pragma unroll 1
        for (int ci = 0; ci < 64; ci += 2) {
            CV4_FMA(IAu, IAv, WA);
            if (ci + 2 < 64) {
                CV4_LOAD(IAu, IAv, ip + (ci + 2)*360);
                CVW_LOAD(WA, wpt + (ci + 2)*20);
            }
            CV4_FMA(IBu, IBv, WB);
            if (ci + 3 < 64) {
                CV4_LOAD(IBu, IBv, ip + (ci + 3)*360);
                CVW_LOAD(WB, wpt + (ci + 3)*20);
            }
        }
        #pragma unroll
        for (int cc = 0; cc < 2; ++cc) {
            #pragma unroll
            for (int iy = 0; iy < 2; ++iy) {
                int mbase = off_m2 + ((b*128 + co + cc)*16 + y0 + iy)*16 + x0;
                int obase = off_o2p + wp*O2PN + ((b*128 + co + cc)*18 + y0 + iy + 1)*20 + x0 + 1;
                #pragma unroll
                for (int p = 0; p < 4; ++p) {
                    float m = ws[mbase+p], o = spk(m);
                    float mn = m + acc[cc][iy][p] - o;
                    ws[mbase+p] = mn;
                    ws[obase+p] = spk(mn);
                }
            }
        }
    } else if (bid < 384) {
        // ---- fc1 8192->1024 + LIF(m4): barrier-free K-loop, acts from L2, 2-deep W prefetch ----
        int jb = bid - 256;
        int w = tid >> 6, l = tid & 63;
        const float* fp = ws + off_f + rp*FBN;
        const float* wb = L1 + (jb*8 + w*2)*8192;
        float acc[2][16] = {};
        float4 wA[2], wB[2];
        #pragma unroll
        for (int jj = 0; jj < 2; ++jj) {
            wA[jj] = ld4(wb + jj*8192 + l*4);
            wB[jj] = ld4(wb + jj*8192 + 256 + l*4);
        }
        for (int c = 0; c < 32; ++c) {
            const float* av = fp + c*256 + l*4;
            #pragma unroll
            for (int b = 0; b < 16; ++b) {
                float4 fv = ld4(av + b*8192);
                acc[0][b] += wA[0].x*fv.x + wA[0].y*fv.y + wA[0].z*fv.z + wA[0].w*fv.w;
                acc[1][b] += wA[1].x*fv.x + wA[1].y*fv.y + wA[1].z*fv.z + wA[1].w*fv.w;
            }
            wA[0] = wB[0]; wA[1] = wB[1];
            if (c < 30) {
                wB[0] = ld4(wb + (c+2)*256 + l*4);
                wB[1] = ld4(wb + 8192 + (c+2)*256 + l*4);
            }
        }
        // pair pre-reduce via shuffle, then stride-33 LDS reduce over 32 partials
        #pragma unroll
        for (int jj = 0; jj < 2; ++jj)
            #pragma unroll
            for (int b = 0; b < 16; ++b) acc[jj][b] += __shfl_xor(acc[jj][b], 1);
        float* rg = sh + w*1056;
        if ((l & 1) == 0) {
            #pragma unroll
            for (int jj = 0; jj < 2; ++jj)
                #pragma unroll
                for (int b = 0; b < 16; ++b) rg[(l>>1)*33 + jj*16 + b] = acc[jj][b];
        }
        __syncthreads();
        if (tid < 128) {
            int w2 = tid >> 5, r = tid & 31, jj = r >> 4, b = r & 15;
            const float* rg2 = sh + w2*1056;
            float sum = 0.0f;
            #pragma unroll
            for (int l2 = 0; l2 < 32; ++l2) sum += rg2[l2*33 + r];
            int j = jb*8 + w2*2 + jj;
            int gi = off_m4 + b*1024 + j;
            float m = ws[gi], o = spk(m);
            float mn = m + sum - o;
            ws[gi] = mn;
            ws[off_o4 + wp*M4N + b*1024 + j] = spk(mn);
        }
    } else if (bid < 640) {
        // ---- encoder (redundant) + conv1 + LIF(m1) + pooled next-spike ----
        int bb = bid - 384;
        int b = bb >> 4, tile = bb & 15;
        int ty = tile >> 2, tx = tile & 3;
        int y0 = ty*8, x0 = tx*8;
        const float* vin  = ws + off_v + rp*VS + b*3072;
        float*       vout = ws + off_v + wp*VS + b*3072;
        const float* sin_ = ws + off_s + rp*VS + b*3072;
        float*       sout = ws + off_s + wp*VS + b*3072;
        const float* xin  = x + b*3072;
        float* sl = sh; // [3][10][12]
        for (int idx = tid; idx < 300; idx += 256) {
            int ci = idx/100, r2 = idx%100, rr = r2/10, cc = r2%10;
            int yy = y0 - 1 + rr, xx = x0 - 1 + cc;
            float sv = 0.0f;
            if ((unsigned)yy < 32u && (unsigned)xx < 32u) {
                int g = ci*1024 + yy*32 + xx;
                float vn = vin[g] + xin[g] - sin_[g];
                sv = vn > 1.0f ? 1.0f : 0.0f;
                if (yy >= y0 && yy < y0+8 && xx >= x0 && xx < x0+8) { vout[g] = vn; sout[g] = sv; }
            }
            sl[(ci*10 + rr)*12 + cc] = sv;
        }
        __syncthreads();
        int tl = tid & 15, cog = tid >> 4;
        int py = (tl >> 2)*2, px = (tl & 3)*2;
        for (int cl = 0; cl < 4; ++cl) {
            int co = cog*4 + cl;
            const float* wtp = ws + off_w1r + co*36;
            float a00=0,a01=0,a10=0,a11=0;
            #pragma unroll
            for (int ci = 0; ci < 3; ++ci) {
                float4 w0 = ld4(wtp + ci*12), w1 = ld4(wtp + ci*12 + 4), w2 = ld4(wtp + ci*12 + 8);
                float wdl[3][3] = {{w0.x,w0.y,w0.z},{w1.x,w1.y,w1.z},{w2.x,w2.y,w2.z}};
                #pragma unroll
                for (int dy = 0; dy < 3; ++dy)
                    #pragma unroll
                    for (int dx = 0; dx < 3; ++dx) {
                        float wvv = wdl[dy][dx];
                        const float* rsl = sl + (ci*10 + py + dy)*12 + px + dx;
                        a00 += rsl[0]  * wvv; a01 += rsl[1]  * wvv;
                        a10 += rsl[12] * wvv; a11 += rsl[13] * wvv;
                    }
            }
            int gy = y0 + py, gx = x0 + px;
            float accs[2][2] = {{a00,a01},{a10,a11}};
            float pooled = 0.0f;
            #pragma unroll
            for (int iy = 0; iy < 2; ++iy)
                #pragma unroll
                for (int ix = 0; ix < 2; ++ix) {
                    int gm = off_m1 + ((b*64 + co)*32 + gy + iy)*32 + gx + ix;
                    float m = ws[gm], o = spk(m);
                    float mn = m + accs[iy][ix] - o;
                    ws[gm] = mn;
                    pooled += spk(mn);
                }
            ws[off_o1p + wp*O1PN + ((b*64 + co)*18 + (gy>>1) + 1)*20 + (gx>>1) + 1] = pooled*0.25f;
        }
    } else if (bid < 896) {
        // ---- fc2 1024->1024 + LIF(m5); 256 blocks x 4 cols, 64-lane K-split ----
        int jb = bid - 640;
        int jg = tid >> 6, l = tid & 63;
        int j  = jb*4 + jg;
        const float* op = ws + off_o4 + rp*M4N;
        const float* wr = L2 + j*1024;
        float acc[16] = {};
        float4 wv[4];
        #pragma unroll
        for (int u = 0; u < 4; ++u) wv[u] = ld4(wr + u*256 + l*4);
        #pragma unroll
        for (int u = 0; u < 4; ++u) {
            int k = u*256 + l*4;
            #pragma unroll
            for (int b = 0; b < 16; ++b) {
                float4 fv = ld4(op + b*1024 + k);
                acc[b] += wv[u].x*fv.x + wv[u].y*fv.y + wv[u].z*fv.z + wv[u].w*fv.w;
            }
        }
        int r = jg*64 + l;
        #pragma unroll
        for (int b = 0; b < 16; ++b) sh[r*17 + b] = acc[b];
        __syncthreads();
        {
            int p = tid >> 2, q = tid & 3;
            float s2 = 0.0f;
            int rb2 = (p >> 4)*64 + q*16, col = p & 15;
            #pragma unroll
            for (int t2 = 0; t2 < 16; ++t2) s2 += sh[(rb2 + t2)*17 + col];
            sh[4352 + tid] = s2;
        }
        __syncthreads();
        if (tid < 64) {
            float sum = sh[4352 + tid*4] + sh[4352 + tid*4 + 1]
                      + sh[4352 + tid*4 + 2] + sh[4352 + tid*4 + 3];
            int jg2 = tid >> 4, b = tid & 15;
            int jj = jb*4 + jg2;
            int gi = off_m5 + b*1024 + jj;
            float m = ws[gi], o = spk(m);
            float mn = m + sum - o;
            ws[gi] = mn;
            ws[off_o5 + wp*M5N + b*1024 + jj] = spk(mn);
        }
    } else {
        // ---- fc3 1024->10, accumulate output membrane ----
        if (tid < 160) {
            int b = tid/10, c = tid - b*10;
            const float* op = ws + off_o5 + rp*M5N + b*1024;
            const float* wr = L3 + c*1024;
            float sum = 0.0f;
            for (int k = 0; k < 1024; k += 4) {
                float4 a = ld4(op + k), wvv = ld4(wr + k);
                sum += a.x*wvv.x + a.y*wvv.y + a.z*wvv.z + a.w*wvv.w;
            }
            out[b*10 + c] += sum;
        }
    }
}

extern "C" void kernel_launch(void* const* d_in, const int* in_sizes, int n_in,
                              void* d_out, int out_size, void* d_ws, size_t ws_size,
                              hipStream_t stream) {
    const float* x  = (const float*)d_in[0];
    const float* W1 = (const float*)d_in[1];
    const float* W2 = (const float*)d_in[2];
    const float* W3 = (const float*)d_in[3];
    const float* L1 = (const float*)d_in[4];
    const float* L2 = (const float*)d_in[5];
    const float* L3 = (const float*)d_in[6];
    float* out = (float*)d_out;
    float* ws  = (float*)d_ws;

    init_k<<<1024, 256, 0, stream>>>(W1, W2, W3, ws, out);
    for (int t = 0; t < 20; ++t)
        step_k<<<897, 256, 0, stream>>>(x, L1, L2, L3, ws, out, t);
}